// Round 3
// baseline (2590.148 us; speedup 1.0000x reference)
//
#include <hip/hip_runtime.h>

// PointNet++ SA module: FPS -> ball query (K nearest within R) -> gather ->
// 3-layer MLP -> masked max aggregation.
//
// B=4 batches, NP=8192 pts, MP=2048 centers/batch, K=64, R=0.2, D_IN=32.
// d_out = [x_out (8192*128) | pos_out (8192*3) | batch_out (8192)] as fp32.
//
// ws layout (bytes):
//   P1  : 0        .. 8388608   (32768 x 64 fp32)  = x @ W1[0:32]
//   W2T : 8388608  .. 8404992   (64x64 fp32, transposed)
//   W3T : 8404992  .. 8437760   (128x64 fp32, transposed)
//   nbr : 8437760  .. 10534912  (8192 x 64 int32, -1 = invalid)

#define BATCH 4
#define NP 8192
#define MP 2048
#define KNN 64
#define DIN 32

// no-canonicalize fmax: operands here are real squared distances (never NaN),
// so the IEEE-mode canonicalization the compiler inserts before v_max for
// bitcast-sourced values is pure overhead.
__device__ __forceinline__ float fmax_nc(float a, float b) {
  float r;
  asm("v_max_f32 %0, %1, %2" : "=v"(r) : "v"(a), "v"(b));
  return r;
}

// One v_max_f32 + DPP step: disabled/invalid source lanes fall back to `old`
// (= v itself, the fmax identity here).  Pure VALU — no LDS latency.
#define DPP_FMAX(v, ctrl)                                                     \
  {                                                                           \
    int _t = __builtin_amdgcn_update_dpp(__float_as_int(v),                   \
                                         __float_as_int(v), (ctrl), 0xF,      \
                                         0xF, false);                         \
    (v) = fmax_nc((v), __int_as_float(_t));                                   \
  }

// One v_min_u32 + DPP step (integer: no canonicalization exists).
#define DPP_MINU(v, ctrl)                                                     \
  {                                                                           \
    unsigned _t = (unsigned)__builtin_amdgcn_update_dpp((int)(v), (int)(v),   \
                                                        (ctrl), 0xF, 0xF,    \
                                                        false);               \
    (v) = ((v) < _t) ? (v) : _t;                                              \
  }

// float2 ext-vector: elementwise ops keep per-element rounding identical to
// the scalar form (same sub/mul/fma contraction) whether packed or not.
typedef float v2f __attribute__((ext_vector_type(2)));

// ------------------------------------------- FPS (+ fused P1 / transposes) -
// Blocks 0..3: FPS, one per batch, 1024 threads (16 waves), 8 pts/thread.
// Blocks 4..2051: P1 = x @ W1[0:32] (16 rows x 64 cols per block).
// Block 2052: W2/W3 transposes.
// The P1/tw blocks fill the 252 CUs left idle by FPS and finish in ~15us.
//
// FPS per serial iteration (2047 iters):
//   stage-1: 6-step DPP wave max (no-canon v_max) -> readlane(63) ->
//   ballot/ctz owner lane -> owner picks first-k coords (descending
//   overwrite) and writes float4{x,y,z,wmax} to its parity slot ->
//   ONE barrier -> stage-2: single ds_read_b128 of 16 slots, 4-step DPP max
//   on .w, ballot -> first wid, winner coords via 3 readlanes from the lane
//   holding that slot (NO second LDS access) -> packed min-update + fold.
// Tie-break = first global index, exactly as jnp.argmax: j = tid*8+k is
// ordered by (wid, lane, k); ballot-ctz picks first lane, descending
// overwrite picks first k, ballot-ctz on slots picks first wid (wave w owns
// j in [512w, 512w+512), so first-wid == first-j).
__global__ __launch_bounds__(1024) void fps_k(const float* __restrict__ pos,
                                              const float* __restrict__ x,
                                              const float* __restrict__ W1,
                                              const float* __restrict__ W2,
                                              const float* __restrict__ W3,
                                              float* __restrict__ pout,
                                              float* __restrict__ bout,
                                              float* __restrict__ P1,
                                              float* __restrict__ W2T,
                                              float* __restrict__ W3T)
{
  const int bid = blockIdx.x;
  const int tid = threadIdx.x;

  if (bid >= BATCH) {
    if (bid < BATCH + 2048) {
      // ---- P1: row j = (bid-4)*16 + tid/64, col c = tid&63 ----
      const int j = (bid - BATCH) * 16 + (tid >> 6);
      const int c = tid & 63;
      const float* __restrict__ xr = x + (size_t)j * DIN;
      float acc = 0.f;
#pragma unroll
      for (int k = 0; k < DIN; k++) acc += xr[k] * W1[k * 64 + c];
      P1[(size_t)j * 64 + c] = acc;
    } else {
      // ---- weight transposes: 64*64 + 128*64 = 12288 elements ----
#pragma unroll
      for (int it = 0; it < 12; it++) {
        const int e = it * 1024 + tid;
        if (e < 64 * 64) {
          const int c = e >> 6, k = e & 63;
          W2T[e] = W2[k * 64 + c];
        } else {
          const int e2 = e - 64 * 64;
          const int c = e2 >> 6, k = e2 & 63;
          W3T[e2] = W3[k * 128 + c];
        }
      }
    }
    return;
  }

  // ------------------------------- FPS ----------------------------------
  const int b = bid;
  const int lane = tid & 63, wid = tid >> 6;
  const float* __restrict__ pb = pos + (size_t)b * NP * 3;
  const int base = tid * 8;

  // batch_out as float values (harness reads d_out as one fp32 buffer)
  bout[b * MP + tid] = (float)b;
  bout[b * MP + 1024 + tid] = (float)b;

  __shared__ __align__(16) float sc[2][16][4];   // parity slots {x,y,z,wmax}

  // --- load 8 points (24 contiguous floats) via 6 float4 loads ---
  float t[24];
  const float4* __restrict__ pv = (const float4*)(pb + (size_t)tid * 24);
#pragma unroll
  for (int q = 0; q < 6; q++) *(float4*)&t[q * 4] = pv[q];

  v2f px[4], py[4], pz[4], d[4];
#pragma unroll
  for (int j = 0; j < 4; j++) {
    px[j].x = t[6 * j + 0]; py[j].x = t[6 * j + 1]; pz[j].x = t[6 * j + 2];
    px[j].y = t[6 * j + 3]; py[j].y = t[6 * j + 4]; pz[j].y = t[6 * j + 5];
  }

  const float c0x = pb[0], c0y = pb[1], c0z = pb[2];
  if (tid == 0) {  // sel[0] = 0
    pout[(size_t)b * MP * 3 + 0] = c0x;
    pout[(size_t)b * MP * 3 + 1] = c0y;
    pout[(size_t)b * MP * 3 + 2] = c0z;
  }

  // initial distances to center 0 (same per-element expression as verified)
  float bv = -1.f;
  {
    const v2f cx = {c0x, c0x}, cy = {c0y, c0y}, cz = {c0z, c0z};
#pragma unroll
    for (int j = 0; j < 4; j++) {
      v2f dx = px[j] - cx, dy = py[j] - cy, dz = pz[j] - cz;
      v2f nd = dx * dx + dy * dy + dz * dz;
      d[j] = nd;
      bv = fmaxf(fmaxf(nd.x, nd.y), bv);     // max3-fusable
    }
  }

  for (int i = 1; i < MP; i++) {
    // --- stage-1: 64-lane max, pure VALU (DPP), result in lane 63 ---
    float v = bv;
    DPP_FMAX(v, 0x111);   // row_shr:1
    DPP_FMAX(v, 0x112);   // row_shr:2
    DPP_FMAX(v, 0x114);   // row_shr:4
    DPP_FMAX(v, 0x118);   // row_shr:8
    DPP_FMAX(v, 0x142);   // row_bcast:15
    DPP_FMAX(v, 0x143);   // row_bcast:31
    const float wmax =
        __int_as_float(__builtin_amdgcn_readlane(__float_as_int(v), 63));

    // owner lane = first lane holding wmax; writes coords + value (16B)
    const unsigned long long m = __ballot(bv == wmax);
    const int src = (int)__builtin_ctzll(m);
    const int p = i & 1;
    if (lane == src) {
      float ox = px[3].y, oy = py[3].y, oz = pz[3].y;   // k=7 seed
#pragma unroll
      for (int k = 6; k >= 0; k--) {         // descending => first k wins
        const float dv = (k & 1) ? d[k >> 1].y : d[k >> 1].x;
        if (dv == wmax) {
          ox = (k & 1) ? px[k >> 1].y : px[k >> 1].x;
          oy = (k & 1) ? py[k >> 1].y : py[k >> 1].x;
          oz = (k & 1) ? pz[k >> 1].y : pz[k >> 1].x;
        }
      }
      float4 q; q.x = ox; q.y = oy; q.z = oz; q.w = wmax;
      *(float4*)&sc[p][wid][0] = q;
    }
    __syncthreads();

    // --- stage-2: 16-slot argmax, ONE ds_read_b128, coords via readlane ---
    const float4 q = *(const float4*)&sc[p][lane & 15][0];  // broadcast reads
    const float v2 = q.w;
    float v2r = v2;
    DPP_FMAX(v2r, 0x111);
    DPP_FMAX(v2r, 0x112);
    DPP_FMAX(v2r, 0x114);
    DPP_FMAX(v2r, 0x118);                    // lane 15 = max of slots 0..15
    const float mv =
        __int_as_float(__builtin_amdgcn_readlane(__float_as_int(v2r), 15));
    const unsigned long long m2 = __ballot(v2 == mv);
    const int mw = (int)__builtin_ctzll(m2);           // first wid among ties
    const float ncx =
        __int_as_float(__builtin_amdgcn_readlane(__float_as_int(q.x), mw));
    const float ncy =
        __int_as_float(__builtin_amdgcn_readlane(__float_as_int(q.y), mw));
    const float ncz =
        __int_as_float(__builtin_amdgcn_readlane(__float_as_int(q.z), mw));

    if (tid == 0) {
      pout[((size_t)b * MP + i) * 3 + 0] = ncx;
      pout[((size_t)b * MP + i) * 3 + 1] = ncy;
      pout[((size_t)b * MP + i) * 3 + 2] = ncz;
    }

    // fused min-update + local value max for next iteration
    const v2f cx = {ncx, ncx}, cy = {ncy, ncy}, cz = {ncz, ncz};
    bv = -1.f;
#pragma unroll
    for (int j = 0; j < 4; j++) {
      v2f dx = px[j] - cx, dy = py[j] - cy, dz = pz[j] - cz;
      v2f nd = dx * dx + dy * dy + dz * dz;
      v2f dn;
      dn.x = fminf(d[j].x, nd.x);
      dn.y = fminf(d[j].y, nd.y);
      d[j] = dn;
      bv = fmaxf(fmaxf(dn.x, dn.y), bv);     // max3-fusable
    }
  }
}

// ---------------------------------------------------------- ball query -----
// One wave (64-thread block) per center. Candidates (d2<=R2) compacted to
// LDS as u64 keys (d2_bits<<32 | idx); 64 rounds of wave-argmin reproduce
// lax.top_k's stable (d2 asc, idx asc) selection exactly.
// The argmin is two 6-step DPP v_min_u32 chains (d2-bits, then idx among
// d2-ties) — pure VALU, replacing the u64 shfl butterfly whose 12 dependent
// ds_bpermutes per round were ~300 serial cycles.
//   correctness: d2 >= 0 so u32 order on d2 bits == float order; the empty
//   sentinel hi=0xFFFFFFFF exceeds every stored d2 (<= R2 bits ~0x3D23D70B);
//   cand[] slots are in ascending idx order and each lane's strict-< local
//   scan keeps its smallest (d2,idx), so min-over-(d2-bits) then
//   min-over-idx-among-ties == min over u64 keys == lax.top_k order.
__global__ __launch_bounds__(64) void ballq_k(const float* __restrict__ pos,
                                              const float* __restrict__ pout,
                                              int* __restrict__ nbr)
{
  const int wg = blockIdx.x;       // center id 0..8191
  const int lane = threadIdx.x;
  const int b = wg >> 11;
  const float* __restrict__ pb = pos + (size_t)b * NP * 3;
  const float cx = pout[(size_t)wg * 3 + 0];
  const float cy = pout[(size_t)wg * 3 + 1];
  const float cz = pout[(size_t)wg * 3 + 2];
  const float R2 = (float)(0.2 * 0.2);   // matches JAX weak-type promotion exactly

  __shared__ unsigned long long cand[1024];
  int cnt = 0;
  for (int basej = 0; basej < NP; basej += 64) {
    const int j = basej + lane;
    float dx = pb[j * 3 + 0] - cx;
    float dy = pb[j * 3 + 1] - cy;
    float dz = pb[j * 3 + 2] - cz;
    float d2 = dx * dx + dy * dy + dz * dz;
    bool in = (d2 <= R2);
    unsigned long long mb = __ballot(in);
    int pre = (int)__popcll(mb & ((1ull << lane) - 1ull));
    int slot = cnt + pre;
    if (in && slot < 1024)
      cand[slot] = ((unsigned long long)__float_as_uint(d2) << 32) | (unsigned int)j;
    cnt += (int)__popcll(mb);
  }
  if (cnt > 1024) cnt = 1024;   // unreachable for this data (max ~360)

  int myout = -1;
  for (int r = 0; r < KNN; r++) {
    unsigned long long v = ~0ull; int slot = -1;
    for (int s = lane; s < cnt; s += 64) {
      unsigned long long c = cand[s];
      if (c < v) { v = c; slot = s; }
    }
    // wave-min of d2 bits (hi32)
    const unsigned hi = (unsigned)(v >> 32);
    unsigned h = hi;
    DPP_MINU(h, 0x111);
    DPP_MINU(h, 0x112);
    DPP_MINU(h, 0x114);
    DPP_MINU(h, 0x118);
    DPP_MINU(h, 0x142);
    DPP_MINU(h, 0x143);
    const unsigned mb = (unsigned)__builtin_amdgcn_readlane((int)h, 63);
    // wave-min of idx among d2-tied lanes
    const unsigned jc = (hi == mb) ? (unsigned)(v & 0xffffffffu) : 0xffffffffu;
    unsigned j2 = jc;
    DPP_MINU(j2, 0x111);
    DPP_MINU(j2, 0x112);
    DPP_MINU(j2, 0x114);
    DPP_MINU(j2, 0x118);
    DPP_MINU(j2, 0x142);
    DPP_MINU(j2, 0x143);
    const unsigned jwin = (unsigned)__builtin_amdgcn_readlane((int)j2, 63);

    if (lane == r) myout = (mb == 0xffffffffu) ? -1 : (int)jwin;
    if (mb != 0xffffffffu && jc == jwin) cand[slot] = ~0ull;  // unique lane
    __syncthreads();
  }
  nbr[(size_t)wg * KNN + lane] = myout;
}

// ------------------------------------------------------- MLP + max agg -----
// One wave (64-thread block) per center, lane = neighbor slot.
// h1 in VGPRs; h2 staged in LDS at stride 68 floats (stride 64 => 64-way
// bank conflict; 68 => conflict-free b128 pattern). Weight reads use
// wave-uniform indices -> scalar (SGPR) loads.
__global__ __launch_bounds__(64) void mlp_k(const float* __restrict__ pos,
    const float* __restrict__ P1, const float* __restrict__ W1,
    const float* __restrict__ b1, const float* __restrict__ W2T,
    const float* __restrict__ b2, const float* __restrict__ W3T,
    const float* __restrict__ b3, const int* __restrict__ nbr,
    const float* __restrict__ pout, float* __restrict__ xout)
{
  __shared__ __align__(16) float h2s[64 * 68];
  const int wg = blockIdx.x;
  const int lane = threadIdx.x;
  const int b = wg >> 11;
  const int idx = nbr[(size_t)wg * KNN + lane];
  const bool valid = idx >= 0;
  const int j = valid ? idx : 0;
  const float cx = pout[(size_t)wg * 3 + 0];
  const float cy = pout[(size_t)wg * 3 + 1];
  const float cz = pout[(size_t)wg * 3 + 2];
  const float* __restrict__ pj = pos + ((size_t)b * NP + j) * 3;
  const float rx = pj[0] - cx, ry = pj[1] - cy, rz = pj[2] - cz;
  const float* __restrict__ p1r =
      (const float*)__builtin_assume_aligned(P1 + ((size_t)b * NP + j) * 64, 16);

  // layer 1: h1 = relu(P1[j] + rel @ W1[32:35] + b1)   (64 VGPRs)
  float h1[64];
#pragma unroll
  for (int k = 0; k < 64; k++) {
    float v = p1r[k] + rx * W1[32 * 64 + k] + ry * W1[33 * 64 + k]
                     + rz * W1[34 * 64 + k] + b1[k];
    h1[k] = fmaxf(v, 0.f);
  }

  // layer 2: h2 = relu(h1 @ W2 + b2) -> LDS
  for (int c4 = 0; c4 < 16; c4++) {
    float a0 = b2[c4 * 4 + 0], a1 = b2[c4 * 4 + 1];
    float a2 = b2[c4 * 4 + 2], a3 = b2[c4 * 4 + 3];
    const float* __restrict__ w0 = W2T + (c4 * 4 + 0) * 64;
    const float* __restrict__ w1 = W2T + (c4 * 4 + 1) * 64;
    const float* __restrict__ w2 = W2T + (c4 * 4 + 2) * 64;
    const float* __restrict__ w3 = W2T + (c4 * 4 + 3) * 64;
#pragma unroll
    for (int k = 0; k < 64; k++) {
      a0 += h1[k] * w0[k]; a1 += h1[k] * w1[k];
      a2 += h1[k] * w2[k]; a3 += h1[k] * w3[k];
    }
    float4 q;
    q.x = fmaxf(a0, 0.f); q.y = fmaxf(a1, 0.f);
    q.z = fmaxf(a2, 0.f); q.w = fmaxf(a3, 0.f);
    *(float4*)&h2s[lane * 68 + c4 * 4] = q;
  }

  // layer 3 + per-channel max over neighbors (relu>=0 and center is always a
  // valid neighbor, so invalid lanes contributing 0 == reference -BIG mask)
  float4 keep = make_float4(0.f, 0.f, 0.f, 0.f);
  const float* __restrict__ h2p = &h2s[lane * 68];
  for (int c4 = 0; c4 < 32; c4++) {
    float a0 = b3[c4 * 4 + 0], a1 = b3[c4 * 4 + 1];
    float a2 = b3[c4 * 4 + 2], a3 = b3[c4 * 4 + 3];
    const float* __restrict__ w0 = W3T + (c4 * 4 + 0) * 64;
    const float* __restrict__ w1 = W3T + (c4 * 4 + 1) * 64;
    const float* __restrict__ w2 = W3T + (c4 * 4 + 2) * 64;
    const float* __restrict__ w3 = W3T + (c4 * 4 + 3) * 64;
#pragma unroll
    for (int k4 = 0; k4 < 16; k4++) {
      float4 h = *(const float4*)&h2p[k4 * 4];
      a0 += h.x * w0[k4 * 4 + 0]; a0 += h.y * w0[k4 * 4 + 1];
      a0 += h.z * w0[k4 * 4 + 2]; a0 += h.w * w0[k4 * 4 + 3];
      a1 += h.x * w1[k4 * 4 + 0]; a1 += h.y * w1[k4 * 4 + 1];
      a1 += h.z * w1[k4 * 4 + 2]; a1 += h.w * w1[k4 * 4 + 3];
      a2 += h.x * w2[k4 * 4 + 0]; a2 += h.y * w2[k4 * 4 + 1];
      a2 += h.z * w2[k4 * 4 + 2]; a2 += h.w * w2[k4 * 4 + 3];
      a3 += h.x * w3[k4 * 4 + 0]; a3 += h.y * w3[k4 * 4 + 1];
      a3 += h.z * w3[k4 * 4 + 2]; a3 += h.w * w3[k4 * 4 + 3];
    }
    a0 = valid ? fmaxf(a0, 0.f) : 0.f;
    a1 = valid ? fmaxf(a1, 0.f) : 0.f;
    a2 = valid ? fmaxf(a2, 0.f) : 0.f;
    a3 = valid ? fmaxf(a3, 0.f) : 0.f;
#pragma unroll
    for (int off = 1; off < 64; off <<= 1) {
      a0 = fmaxf(a0, __shfl_xor(a0, off));
      a1 = fmaxf(a1, __shfl_xor(a1, off));
      a2 = fmaxf(a2, __shfl_xor(a2, off));
      a3 = fmaxf(a3, __shfl_xor(a3, off));
    }
    if (lane == c4) { keep.x = a0; keep.y = a1; keep.z = a2; keep.w = a3; }
  }
  if (lane < 32)
    *(float4*)&xout[(size_t)wg * 128 + lane * 4] = keep;
}

// --------------------------------------------------------------- launch ----
extern "C" void kernel_launch(void* const* d_in, const int* in_sizes, int n_in,
                              void* d_out, int out_size, void* d_ws, size_t ws_size,
                              hipStream_t stream)
{
  const float* x   = (const float*)d_in[0];
  const float* pos = (const float*)d_in[1];
  // d_in[2] = batch (unused; layout is implicit)
  const float* W1 = (const float*)d_in[3];
  const float* b1 = (const float*)d_in[4];
  const float* W2 = (const float*)d_in[5];
  const float* b2 = (const float*)d_in[6];
  const float* W3 = (const float*)d_in[7];
  const float* b3 = (const float*)d_in[8];

  float* out  = (float*)d_out;
  float* xout = out;                      // 8192*128
  float* pout = out + 8192 * 128;         // 8192*3
  float* bout = out + 8192 * 128 + 8192 * 3;  // 8192

  char* ws = (char*)d_ws;
  float* P1  = (float*)ws;
  float* W2T = (float*)(ws + 8388608);
  float* W3T = (float*)(ws + 8404992);
  int*   nbr = (int*)(ws + 8437760);

  // fps blocks (0..3) + P1 blocks (4..2051) + transpose block (2052)
  fps_k<<<dim3(BATCH + 2048 + 1), dim3(1024), 0, stream>>>(
      pos, x, W1, W2, W3, pout, bout, P1, W2T, W3T);
  ballq_k<<<dim3(BATCH * MP), dim3(64), 0, stream>>>(pos, pout, nbr);
  mlp_k<<<dim3(BATCH * MP), dim3(64), 0, stream>>>(pos, P1, W1, b1, W2T, b2,
                                                   W3T, b3, nbr, pout, xout);
}